// Round 1
// baseline (446.319 us; speedup 1.0000x reference)
//
#include <hip/hip_runtime.h>
#include <stdint.h>

#define D 64
#define NT 8
#define CHUNK 1024
#define BLOCK 256

typedef __attribute__((ext_vector_type(8))) short short8;   // 8 bf16 (4 VGPRs)
typedef __attribute__((ext_vector_type(4))) float f32x4;    // 4 fp32

__device__ __forceinline__ unsigned short f2bf(float f) {
    union { float f; unsigned u; } v; v.f = f;
    unsigned u = v.u;
    // round-to-nearest-even truncation to bf16
    unsigned r = (u + 0x7FFFu + ((u >> 16) & 1u)) >> 16;
    return (unsigned short)r;
}

__global__ void __launch_bounds__(BLOCK)
edge_mlp_kernel(const float* __restrict__ ef, const int* __restrict__ types,
                const float* __restrict__ W, const float* __restrict__ Bv,
                float* __restrict__ out, int E)
{
    __shared__ unsigned short bucket[CHUNK];
    __shared__ unsigned cnt[NT];
    __shared__ unsigned startoff[NT];
    __shared__ unsigned cursor[NT];

    const int tid  = threadIdx.x;
    const int base = blockIdx.x * CHUNK;
    const int clen = min(CHUNK, E - base);
    if (clen <= 0) return;   // uniform per block

    if (tid < NT) cnt[tid] = 0;
    __syncthreads();

    // ---- Phase 1: bucket edge indices by type (histogram + scatter) ----
    int myt[CHUNK / BLOCK];
#pragma unroll
    for (int i = 0; i < CHUNK / BLOCK; ++i) {
        int idx = tid + i * BLOCK;
        int t = -1;
        if (idx < clen) {
            t = types[base + idx];
            atomicAdd(&cnt[t], 1u);
        }
        myt[i] = t;
    }
    __syncthreads();
    if (tid == 0) {
        unsigned s = 0;
        for (int t = 0; t < NT; ++t) { startoff[t] = s; cursor[t] = s; s += cnt[t]; }
    }
    __syncthreads();
#pragma unroll
    for (int i = 0; i < CHUNK / BLOCK; ++i) {
        if (myt[i] >= 0) {
            unsigned pos = atomicAdd(&cursor[myt[i]], 1u);
            bucket[pos] = (unsigned short)(tid + i * BLOCK);
        }
    }
    __syncthreads();

    // ---- Phase 2: each wave owns 2 types; W as register-resident B-frags ----
    const int wave = tid >> 6;
    const int lane = tid & 63;
    const int n = lane & 15;   // output column within a 16-block / A row m
    const int g = lane >> 4;   // quad index

    for (int ti = 0; ti < 2; ++ti) {
        const int t = wave * 2 + ti;
        const unsigned V  = cnt[t];
        if (V == 0) continue;
        const unsigned bs = startoff[t];

        // B-frag layout: lane holds B[k = g*8+j][col = n] for kblk,nblk
        short8 bf[2][4];
        const float* Wt = W + (size_t)t * D * D;
#pragma unroll
        for (int kb = 0; kb < 2; ++kb) {
#pragma unroll
            for (int nb = 0; nb < 4; ++nb) {
                short8 f;
#pragma unroll
                for (int j = 0; j < 8; ++j) {
                    float w = Wt[(size_t)(kb * 32 + g * 8 + j) * D + nb * 16 + n];
                    f[j] = (short)f2bf(w);
                }
                bf[kb][nb] = f;
            }
        }
        float bias[4];
#pragma unroll
        for (int nb = 0; nb < 4; ++nb) bias[nb] = Bv[t * D + nb * 16 + n];

        const unsigned nbatch = (V + 15u) >> 4;
        for (unsigned b = 0; b < nbatch; ++b) {
            const unsigned p0 = b << 4;
            // A-frag gather: lane's edge index m = n (lane&15)
            unsigned pm = p0 + (unsigned)n;
            if (pm >= V) pm = V - 1;               // clamp for ragged tail
            const int gidx = base + (int)bucket[bs + pm];
            const float* row = ef + (size_t)gidx * D;

            // A[m][k]: k = kblk*32 + g*8 + j  -> 8 consecutive floats per frag
            f32x4 a0 = *(const f32x4*)(row + g * 8);
            f32x4 a1 = *(const f32x4*)(row + g * 8 + 4);
            f32x4 a2 = *(const f32x4*)(row + 32 + g * 8);
            f32x4 a3 = *(const f32x4*)(row + 32 + g * 8 + 4);

            short8 fa0, fa1;
#pragma unroll
            for (int j = 0; j < 4; ++j) {
                fa0[j]     = (short)f2bf(a0[j]);
                fa0[j + 4] = (short)f2bf(a1[j]);
                fa1[j]     = (short)f2bf(a2[j]);
                fa1[j + 4] = (short)f2bf(a3[j]);
            }

            f32x4 acc[4];
#pragma unroll
            for (int nb = 0; nb < 4; ++nb) acc[nb] = (f32x4){0.f, 0.f, 0.f, 0.f};

#pragma unroll
            for (int nb = 0; nb < 4; ++nb) {
                acc[nb] = __builtin_amdgcn_mfma_f32_16x16x32_bf16(fa0, bf[0][nb], acc[nb], 0, 0, 0);
                acc[nb] = __builtin_amdgcn_mfma_f32_16x16x32_bf16(fa1, bf[1][nb], acc[nb], 0, 0, 0);
            }

            // Epilogue: C/D layout col = lane&15, row = g*4 + reg
#pragma unroll
            for (int r = 0; r < 4; ++r) {
                const int rowpos = g * 4 + r;
                const int sidx = __shfl(gidx, rowpos);   // lane rowpos holds m = rowpos
                if (p0 + (unsigned)rowpos < V) {
                    float* orow = out + (size_t)sidx * D;
#pragma unroll
                    for (int nb = 0; nb < 4; ++nb) {
                        float v = acc[nb][r] + bias[nb];
                        orow[nb * 16 + n] = v > 0.f ? v : 0.f;
                    }
                }
            }
        }
    }
}

extern "C" void kernel_launch(void* const* d_in, const int* in_sizes, int n_in,
                              void* d_out, int out_size, void* d_ws, size_t ws_size,
                              hipStream_t stream) {
    const float* ef    = (const float*)d_in[0];
    const int*   types = (const int*)d_in[1];
    const float* W     = (const float*)d_in[2];
    const float* Bv    = (const float*)d_in[3];
    float* out = (float*)d_out;
    const int E = in_sizes[1];
    const int grid = (E + CHUNK - 1) / CHUNK;
    hipLaunchKernelGGL(edge_mlp_kernel, dim3(grid), dim3(BLOCK), 0, stream,
                       ef, types, W, Bv, out, E);
}